// Round 14
// baseline (980.862 us; speedup 1.0000x reference)
//
#include <hip/hip_runtime.h>
#include <hip/hip_bf16.h>
#include <math.h>

#define NB    4
#define NTOK  8192
#define DIM   1024
#define HDIM  512
#define NKEEP 4096
#define MARG  0.06f
#define A2_MAXC 1024

typedef __attribute__((ext_vector_type(8))) short bf16x8;
typedef __attribute__((ext_vector_type(4))) float f32x4;

__device__ __forceinline__ short f2bf(float x) {
    unsigned u = __builtin_bit_cast(unsigned, x);
    unsigned r = (u + 0x7FFFu + ((u >> 16) & 1u)) >> 16;
    return (short)r;
}
__device__ __forceinline__ float gelu_exact(float h) {
    return 0.5f * h * (1.0f + erff(h * 0.70710678118654752f));
}
__device__ __forceinline__ unsigned fkey(float x) {
    const unsigned u = __builtin_bit_cast(unsigned, x);
    return u ^ ((u >> 31) ? 0xFFFFFFFFu : 0x80000000u);
}

// ---------------------------------------------------------------------------
// P0: repack W1 into bf16 MFMA-B fragment order.
// ---------------------------------------------------------------------------
__global__ __launch_bounds__(256)
void dtr_prep_w1(const float* __restrict__ W1, short* __restrict__ w1f)
{
    const int idx = blockIdx.x * 256 + threadIdx.x;
    const int e = idx & 7, l = (idx >> 3) & 63, t = (idx >> 9) & 31, s = idx >> 14;
    const int k = s * 32 + (l >> 4) * 8 + e;
    const int n = t * 16 + (l & 15);
    w1f[idx] = f2bf(W1[(size_t)k * HDIM + n]);
}

// ---------------------------------------------------------------------------
// A1 (real, = R13 v7, unchanged): 1024 blocks x 512 thr, 32 tok/block,
// barrier-free K-loop, 4 waves/SIMD. 104 us measured.
// ---------------------------------------------------------------------------
__global__ __launch_bounds__(512, 4)
void dtr_a1_approx(const float* __restrict__ tokens,
                   const short* __restrict__ w1f,
                   const float* __restrict__ b1g,
                   const float* __restrict__ W2,
                   const float* __restrict__ b2g,
                   float* __restrict__ sapx)
{
    __shared__ __align__(16) short Af[32768];
    __shared__ float part[8][32];

    const int tid  = threadIdx.x;
    const int w    = tid >> 6;
    const int lane = tid & 63;
    const int cl   = lane & 15;
    const int kg   = lane >> 4;
    const int tok0 = blockIdx.x * 32;

#pragma unroll
    for (int p = 0; p < 8; ++p) {
        const int idx = tid + p * 512;
        const int at  = idx >> 11;
        const int s   = (idx >> 6) & 31;
        const int l   = idx & 63;
        const int row = tok0 + at * 16 + (l & 15);
        const int kc  = s * 32 + (l >> 4) * 8;
        const float* g = tokens + (size_t)row * DIM + kc;
        const float4 f0 = *reinterpret_cast<const float4*>(g);
        const float4 f1 = *reinterpret_cast<const float4*>(g + 4);
        bf16x8 v;
        v[0] = f2bf(f0.x); v[1] = f2bf(f0.y); v[2] = f2bf(f0.z); v[3] = f2bf(f0.w);
        v[4] = f2bf(f1.x); v[5] = f2bf(f1.y); v[6] = f2bf(f1.z); v[7] = f2bf(f1.w);
        *reinterpret_cast<bf16x8*>(&Af[idx * 8]) = v;
    }
    __syncthreads();

    f32x4 acc[2][4];
#pragma unroll
    for (int at = 0; at < 2; ++at)
#pragma unroll
        for (int t = 0; t < 4; ++t) acc[at][t] = (f32x4){0.f, 0.f, 0.f, 0.f};

    const short* bw = w1f + ((size_t)(w * 4) * 64 + lane) * 8;

    auto loadB = [&](int s, bf16x8* d) {
        const short* p = bw + (size_t)s * 16384;
#pragma unroll
        for (int t = 0; t < 4; ++t)
            d[t] = *reinterpret_cast<const bf16x8*>(p + t * 512);
    };
    auto compute = [&](int s, const bf16x8* bv) {
        bf16x8 af[2];
#pragma unroll
        for (int at = 0; at < 2; ++at)
            af[at] = *reinterpret_cast<const bf16x8*>(
                &Af[((at * 32 + s) * 64 + lane) * 8]);
#pragma unroll
        for (int t = 0; t < 4; ++t)
#pragma unroll
            for (int at = 0; at < 2; ++at)
                acc[at][t] = __builtin_amdgcn_mfma_f32_16x16x32_bf16(
                    af[at], bv[t], acc[at][t], 0, 0, 0);
    };

    bf16x8 bA[4], bB[4];
    loadB(0, bA);
#pragma unroll
    for (int s = 0; s < 32; s += 2) {
        if (s + 1 < 32) loadB(s + 1, bB);
        compute(s, bA);
        if (s + 2 < 32) loadB(s + 2, bA);
        compute(s + 1, bB);
    }

    float pr[2][4];
#pragma unroll
    for (int at = 0; at < 2; ++at)
#pragma unroll
        for (int r = 0; r < 4; ++r) pr[at][r] = 0.f;
#pragma unroll
    for (int t = 0; t < 4; ++t) {
        const int n = (w * 4 + t) * 16 + cl;
        const float b1v = b1g[n], w2v = W2[n];
#pragma unroll
        for (int at = 0; at < 2; ++at)
#pragma unroll
            for (int r = 0; r < 4; ++r)
                pr[at][r] = fmaf(gelu_exact(acc[at][t][r] + b1v), w2v, pr[at][r]);
    }
#pragma unroll
    for (int at = 0; at < 2; ++at)
#pragma unroll
        for (int r = 0; r < 4; ++r) {
            float p = pr[at][r];
#pragma unroll
            for (int off = 1; off < 16; off <<= 1)
                p += __shfl_xor(p, off, 64);
            pr[at][r] = p;
        }
    if (cl == 0) {
#pragma unroll
        for (int at = 0; at < 2; ++at)
#pragma unroll
            for (int r = 0; r < 4; ++r)
                part[w][at * 16 + kg * 4 + r] = pr[at][r];
    }
    __syncthreads();
    if (tid < 32) {
        float s = b2g[0];
#pragma unroll
        for (int ww = 0; ww < 8; ++ww) s += part[ww][tid];
        sapx[tok0 + tid] = s;
    }
}

// ---------------------------------------------------------------------------
// A1 ABLATION PROBES (diagnostic; outputs dead, written to scratch).
// MODE: 0=FULL 1=NOB(const B) 2=NOSTAGE(const A) 3=NOEPI 4=MIN 5=NOMFMA
// ---------------------------------------------------------------------------
template<int MODE>
__global__ __launch_bounds__(512, 4)
void dtr_a1_probe(const float* __restrict__ tokens,
                  const short* __restrict__ w1f,
                  const float* __restrict__ b1g,
                  const float* __restrict__ W2,
                  const float* __restrict__ b2g,
                  float* __restrict__ outp)
{
    constexpr bool DO_STAGE = (MODE != 2 && MODE != 4);
    constexpr bool DO_B     = (MODE != 1 && MODE != 4);
    constexpr bool DO_MFMA  = (MODE != 5);
    constexpr bool DO_EPI   = (MODE <= 2);

    __shared__ __align__(16) short Af[32768];
    __shared__ float part[8][32];

    const int tid  = threadIdx.x;
    const int w    = tid >> 6;
    const int lane = tid & 63;
    const int cl   = lane & 15;
    const int kg   = lane >> 6 == 0 ? (lane >> 4) : (lane >> 4); // = lane>>4
    const int tok0 = blockIdx.x * 32;

    if constexpr (DO_STAGE) {
#pragma unroll
        for (int p = 0; p < 8; ++p) {
            const int idx = tid + p * 512;
            const int at  = idx >> 11;
            const int s   = (idx >> 6) & 31;
            const int l   = idx & 63;
            const int row = tok0 + at * 16 + (l & 15);
            const int kc  = s * 32 + (l >> 4) * 8;
            const float* g = tokens + (size_t)row * DIM + kc;
            const float4 f0 = *reinterpret_cast<const float4*>(g);
            const float4 f1 = *reinterpret_cast<const float4*>(g + 4);
            bf16x8 v;
            v[0] = f2bf(f0.x); v[1] = f2bf(f0.y); v[2] = f2bf(f0.z); v[3] = f2bf(f0.w);
            v[4] = f2bf(f1.x); v[5] = f2bf(f1.y); v[6] = f2bf(f1.z); v[7] = f2bf(f1.w);
            *reinterpret_cast<bf16x8*>(&Af[idx * 8]) = v;
        }
        __syncthreads();
    }

    f32x4 acc[2][4];
#pragma unroll
    for (int at = 0; at < 2; ++at)
#pragma unroll
        for (int t = 0; t < 4; ++t) acc[at][t] = (f32x4){0.f, 0.f, 0.f, 0.f};

    const short* bw = w1f + ((size_t)(w * 4) * 64 + lane) * 8;
    bf16x8 cbf;
#pragma unroll
    for (int e = 0; e < 8; ++e) cbf[e] = (short)0x3F80;   // bf16 1.0

    auto loadB = [&](int s, bf16x8* d) {
        if constexpr (DO_B) {
            const short* p = bw + (size_t)s * 16384;
#pragma unroll
            for (int t = 0; t < 4; ++t)
                d[t] = *reinterpret_cast<const bf16x8*>(p + t * 512);
        } else {
#pragma unroll
            for (int t = 0; t < 4; ++t) d[t] = cbf;
        }
    };
    auto compute = [&](int s, const bf16x8* bv) {
        bf16x8 af[2];
        if constexpr (DO_STAGE) {
#pragma unroll
            for (int at = 0; at < 2; ++at)
                af[at] = *reinterpret_cast<const bf16x8*>(
                    &Af[((at * 32 + s) * 64 + lane) * 8]);
        } else {
#pragma unroll
            for (int at = 0; at < 2; ++at) af[at] = cbf;
        }
        if constexpr (DO_MFMA) {
#pragma unroll
            for (int t = 0; t < 4; ++t)
#pragma unroll
                for (int at = 0; at < 2; ++at)
                    acc[at][t] = __builtin_amdgcn_mfma_f32_16x16x32_bf16(
                        af[at], bv[t], acc[at][t], 0, 0, 0);
        } else {
            // keep loads live without MFMA (rule #17): vector adds on payload
#pragma unroll
            for (int t = 0; t < 4; ++t)
#pragma unroll
                for (int at = 0; at < 2; ++at)
                    acc[at][t] += __builtin_bit_cast(f32x4, bv[t])
                                + __builtin_bit_cast(f32x4, af[at]);
        }
    };

    bf16x8 bA[4], bB[4];
    loadB(0, bA);
#pragma unroll
    for (int s = 0; s < 32; s += 2) {
        if (s + 1 < 32) loadB(s + 1, bB);
        compute(s, bA);
        if (s + 2 < 32) loadB(s + 2, bA);
        compute(s + 1, bB);
    }

    if constexpr (DO_EPI) {
        float pr[2][4];
#pragma unroll
        for (int at = 0; at < 2; ++at)
#pragma unroll
            for (int r = 0; r < 4; ++r) pr[at][r] = 0.f;
#pragma unroll
        for (int t = 0; t < 4; ++t) {
            const int n = (w * 4 + t) * 16 + cl;
            const float b1v = b1g[n], w2v = W2[n];
#pragma unroll
            for (int at = 0; at < 2; ++at)
#pragma unroll
                for (int r = 0; r < 4; ++r)
                    pr[at][r] = fmaf(gelu_exact(acc[at][t][r] + b1v), w2v, pr[at][r]);
        }
#pragma unroll
        for (int at = 0; at < 2; ++at)
#pragma unroll
            for (int r = 0; r < 4; ++r) {
                float p = pr[at][r];
#pragma unroll
                for (int off = 1; off < 16; off <<= 1)
                    p += __shfl_xor(p, off, 64);
                pr[at][r] = p;
            }
        if (cl == 0) {
#pragma unroll
            for (int at = 0; at < 2; ++at)
#pragma unroll
                for (int r = 0; r < 4; ++r)
                    part[w][at * 16 + kg * 4 + r] = pr[at][r];
        }
        __syncthreads();
        if (tid < 32) {
            float s = b2g[0];
#pragma unroll
            for (int ww = 0; ww < 8; ++ww) s += part[ww][tid];
            outp[(size_t)blockIdx.x * 32 + tid] = s;
        }
    } else {
        // raw drain: keep every acc element live
        float s = 0.f;
#pragma unroll
        for (int at = 0; at < 2; ++at)
#pragma unroll
            for (int t = 0; t < 4; ++t)
#pragma unroll
                for (int r = 0; r < 4; ++r) s += acc[at][t][r];
        if (lane == 0) outp[(size_t)blockIdx.x * 8 + w] = s;
    }
}

// ---------------------------------------------------------------------------
__device__ __forceinline__ int blk_excl_scan_1024(int v, int tid, int* lds, int* tot)
{
    const int lane = tid & 63;
    const int wid  = tid >> 6;
    int x = v;
#pragma unroll
    for (int d = 1; d < 64; d <<= 1) {
        const int y = __shfl_up(x, d, 64);
        if (lane >= d) x += y;
    }
    if (lane == 63) lds[wid] = x;
    __syncthreads();
    if (wid == 0) {
        int ww = (lane < 16) ? lds[lane] : 0;
#pragma unroll
        for (int d = 1; d < 16; d <<= 1) {
            const int y = __shfl_up(ww, d, 64);
            if (lane >= d) ww += y;
        }
        if (lane < 16) lds[lane] = ww;
    }
    __syncthreads();
    const int wave_off = (wid == 0) ? 0 : lds[wid - 1];
    const int total    = lds[15];
    __syncthreads();
    *tot = total;
    return wave_off + x - v;
}

// ---------------------------------------------------------------------------
__global__ __launch_bounds__(1024)
void dtr_b1_cand(const float* __restrict__ sapx,
                 float* __restrict__ T_out, int* __restrict__ cnt_out,
                 int* __restrict__ cand)
{
    __shared__ int hist[256];
    __shared__ int scan_lds[16];
    __shared__ unsigned sh_pref;
    __shared__ int sh_rank;
    const int b = blockIdx.x, tid = threadIdx.x;
    const float* s = sapx + (size_t)b * NTOK;

    const int i0 = tid * 8;
    unsigned keys[8];
    float sc[8];
#pragma unroll
    for (int q = 0; q < 8; ++q) {
        sc[q] = s[i0 + q];
        keys[q] = fkey(sc[q]);
    }
    if (tid == 0) { sh_pref = 0u; sh_rank = NKEEP; }

    for (int level = 3; level >= 0; --level) {
        const int sh = level * 8;
        if (tid < 256) hist[tid] = 0;
        __syncthreads();
        const unsigned pref = sh_pref;
        const int rank = sh_rank;
#pragma unroll
        for (int q = 0; q < 8; ++q) {
            const unsigned u = keys[q];
            const bool match = (level == 3) || (((u ^ pref) >> (sh + 8)) == 0u);
            if (match) atomicAdd(&hist[(u >> sh) & 255], 1);
        }
        __syncthreads();
        const int v = (tid < 256) ? hist[255 - tid] : 0;
        int tot;
        const int pos = blk_excl_scan_1024(v, tid, scan_lds, &tot);
        if (tid < 256 && pos < rank && rank <= pos + v) {
            sh_pref = pref | ((unsigned)(255 - tid) << sh);
            sh_rank = rank - pos;
        }
        __syncthreads();
    }
    const unsigned ku = sh_pref;
    const unsigned tu = (ku & 0x80000000u) ? (ku ^ 0x80000000u) : ~ku;
    const float T = __builtin_bit_cast(float, tu);
    if (tid == 0) T_out[b] = T;

    int cf[8], cs = 0;
#pragma unroll
    for (int q = 0; q < 8; ++q) {
        cf[q] = (sc[q] >= T - MARG) && (sc[q] <= T + MARG);
        cs += cf[q];
    }
    int tot;
    int pos = blk_excl_scan_1024(cs, tid, scan_lds, &tot);
#pragma unroll
    for (int q = 0; q < 8; ++q)
        if (cf[q]) cand[(size_t)b * NTOK + pos++] = i0 + q;
    if (tid == 0) cnt_out[b] = (tot < A2_MAXC) ? tot : A2_MAXC;
}

// ---------------------------------------------------------------------------
__global__ __launch_bounds__(256)
void dtr_a2_rescore(const float* __restrict__ tokens,
                    const float* __restrict__ W1,
                    const float* __restrict__ b1g,
                    const float* __restrict__ W2,
                    const float* __restrict__ b2g,
                    const int* __restrict__ cnt_in,
                    const int* __restrict__ cand,
                    float* __restrict__ sex)
{
    __shared__ __align__(16) float tk[8][DIM];
    __shared__ float red[8][4];
    const int tid = threadIdx.x;
    const int b   = blockIdx.x >> 7;
    const int grp = blockIdx.x & 127;
    const int cnt = cnt_in[b];
    const int base = grp * 8;
    if (base >= cnt) return;

    int ctk[8];
#pragma unroll
    for (int c = 0; c < 8; ++c) {
        const int slot = base + c;
        ctk[c] = cand[(size_t)b * NTOK + (slot < cnt ? slot : base)];
    }
#pragma unroll
    for (int c = 0; c < 8; ++c) {
        const float4 v = *reinterpret_cast<const float4*>(
            tokens + ((size_t)b * NTOK + ctk[c]) * DIM + tid * 4);
        *reinterpret_cast<float4*>(&tk[c][tid * 4]) = v;
    }
    __syncthreads();

    const int j = tid * 2;
    float acc0[8], acc1[8];
#pragma unroll
    for (int c = 0; c < 8; ++c) { acc0[c] = 0.f; acc1[c] = 0.f; }

    for (int k0 = 0; k0 < DIM; k0 += 4) {
        float4 a[8];
#pragma unroll
        for (int c = 0; c < 8; ++c)
            a[c] = *reinterpret_cast<const float4*>(&tk[c][k0]);
#pragma unroll
        for (int kk = 0; kk < 4; ++kk) {
            const float2 wv = *reinterpret_cast<const float2*>(
                &W1[(size_t)(k0 + kk) * HDIM + j]);
#pragma unroll
            for (int c = 0; c < 8; ++c) {
                const float av = (kk == 0) ? a[c].x : (kk == 1) ? a[c].y
                               : (kk == 2) ? a[c].z : a[c].w;
                acc0[c] = fmaf(av, wv.x, acc0[c]);
                acc1[c] = fmaf(av, wv.y, acc1[c]);
            }
        }
    }

    const float b1v0 = b1g[j], b1v1 = b1g[j + 1];
    const float w20  = W2[j],  w21  = W2[j + 1];
    const int lane = tid & 63, w4 = tid >> 6;
#pragma unroll
    for (int c = 0; c < 8; ++c) {
        float p = fmaf(gelu_exact(acc0[c] + b1v0), w20,
                       gelu_exact(acc1[c] + b1v1) * w21);
#pragma unroll
        for (int off = 32; off > 0; off >>= 1)
            p += __shfl_xor(p, off, 64);
        if (lane == 0) red[c][w4] = p;
    }
    __syncthreads();
    if (tid < 8) {
        const int slot = base + tid;
        if (slot < cnt) {
            const float sv = red[tid][0] + red[tid][1] + red[tid][2]
                           + red[tid][3] + b2g[0];
            sex[(size_t)b * NTOK + cand[(size_t)b * NTOK + slot]] = sv;
        }
    }
}

// ---------------------------------------------------------------------------
__global__ __launch_bounds__(1024)
void dtr_b2_select(const float* __restrict__ sapx,
                   const float* __restrict__ sex,
                   const float* __restrict__ T_in,
                   const int* __restrict__ cnt_in,
                   const int* __restrict__ cand,
                   int* __restrict__ idx_out,
                   float* __restrict__ mask_out)
{
    __shared__ int hist[256];
    __shared__ int scan_lds[16];
    __shared__ unsigned sh_pref;
    __shared__ int sh_rank;
    __shared__ unsigned char kb[NTOK];
    const int b = blockIdx.x, tid = threadIdx.x;
    const float T  = T_in[b];
    const int  cnt = cnt_in[b];
    const float* s = sapx + (size_t)b * NTOK;

    const int i0 = tid * 8;
    int df[8], dsum = 0;
#pragma unroll
    for (int q = 0; q < 8; ++q) {
        df[q] = s[i0 + q] > T + MARG;
        dsum += df[q];
    }
    int n_in;
    (void)blk_excl_scan_1024(dsum, tid, scan_lds, &n_in);
    const int r = NKEEP - n_in;

    const bool valid = tid < cnt;
    const int  ctok  = valid ? cand[(size_t)b * NTOK + tid] : 0;
    const unsigned key = valid ? fkey(sex[(size_t)b * NTOK + ctok]) : 0u;
    for (int i = tid; i < NTOK; i += 1024) kb[i] = 0;
    if (tid == 0) { sh_pref = 0u; sh_rank = r; }

    for (int level = 3; level >= 0; --level) {
        const int sh = level * 8;
        if (tid < 256) hist[tid] = 0;
        __syncthreads();
        const unsigned pref = sh_pref;
        const int rank = sh_rank;
        const bool match = valid &&
            (level == 3 || (((key ^ pref) >> (sh + 8)) == 0u));
        if (match) atomicAdd(&hist[(key >> sh) & 255], 1);
        __syncthreads();
        const int v = (tid < 256) ? hist[255 - tid] : 0;
        int tot;
        const int pos = blk_excl_scan_1024(v, tid, scan_lds, &tot);
        if (tid < 256 && pos < rank && rank <= pos + v) {
            sh_pref = pref | ((unsigned)(255 - tid) << sh);
            sh_rank = rank - pos;
        }
        __syncthreads();
    }
    const unsigned Tkey = sh_pref;

    const int gt = valid && key > Tkey;
    const int eq = valid && key == Tkey;
    int tot_g, tot_e;
    (void)blk_excl_scan_1024(gt, tid, scan_lds, &tot_g);
    const int pos_e = blk_excl_scan_1024(eq, tid, scan_lds, &tot_e);
    const int need = r - tot_g;
    if ((gt || (eq && pos_e < need)) && valid) kb[ctok] = 1;
    __syncthreads();

    int kf[8], ks = 0;
#pragma unroll
    for (int q = 0; q < 8; ++q) {
        kf[q] = df[q] | (int)kb[i0 + q];
        ks += kf[q];
    }
    int tot;
    int pos = blk_excl_scan_1024(ks, tid, scan_lds, &tot);
#pragma unroll
    for (int q = 0; q < 8; ++q) {
        mask_out[(size_t)b * NTOK + i0 + q] = kf[q] ? 1.0f : 0.0f;
        if (kf[q]) idx_out[(size_t)b * NKEEP + pos++] = i0 + q;
    }
}

// ---------------------------------------------------------------------------
__global__ __launch_bounds__(256)
void dtr_gather_kernel(const float* __restrict__ tokens,
                       const int* __restrict__ idx,
                       float* __restrict__ selected)
{
    const int g   = blockIdx.x;
    const int b   = g >> 12;
    const int src = idx[g];
    const float4* sp = reinterpret_cast<const float4*>(
        tokens + ((size_t)b * NTOK + (size_t)src) * DIM);
    float4* dp = reinterpret_cast<float4*>(selected + (size_t)g * DIM);
    dp[threadIdx.x] = sp[threadIdx.x];
}

// ---------------------------------------------------------------------------
extern "C" void kernel_launch(void* const* d_in, const int* in_sizes, int n_in,
                              void* d_out, int out_size, void* d_ws, size_t ws_size,
                              hipStream_t stream)
{
    const float* tokens = (const float*)d_in[0];
    const float* W1     = (const float*)d_in[1];
    const float* b1     = (const float*)d_in[2];
    const float* W2     = (const float*)d_in[3];
    const float* b2     = (const float*)d_in[4];

    float* out      = (float*)d_out;
    float* selected = out;
    float* mask     = out + (size_t)NB * NKEEP * DIM;

    char* w = (char*)d_ws;
    float* sapx = (float*)(w);                 // 4*8192 f32
    float* sex  = (float*)(w + 131072);        // 4*8192 f32
    float* Tpx  = (float*)(w + 262144);        // 4 f32
    int*   ccnt = (int*)  (w + 262160);        // 4 i32
    int*   cand = (int*)  (w + 262400);        // 4*8192 i32
    short* w1f  = (short*)(w + 393472);        // 1 MB bf16
    int*   idx  = (int*)  (w + 1441792);       // 4*4096 i32
    float* probe = (float*)(w + 1507328);      // 128 KB probe sink (dead)

    // --- real pipeline (unchanged from R13; output must pass) ---
    dtr_prep_w1<<<2048, 256, 0, stream>>>(W1, w1f);
    dtr_a1_approx<<<(NB * NTOK) / 32, 512, 0, stream>>>(tokens, w1f, b1, W2, b2, sapx);
    dtr_b1_cand<<<NB, 1024, 0, stream>>>(sapx, Tpx, ccnt, cand);
    dtr_a2_rescore<<<NB * 128, 256, 0, stream>>>(tokens, W1, b1, W2, b2, ccnt, cand, sex);
    dtr_b2_select<<<NB, 1024, 0, stream>>>(sapx, sex, Tpx, ccnt, cand, idx, mask);
    dtr_gather_kernel<<<NB * NKEEP, 256, 0, stream>>>(tokens, idx, selected);

    // --- a1 ablation probes (diagnostic only; outputs dead) ---
    const int pg = (NB * NTOK) / 32;
    dtr_a1_probe<0><<<pg, 512, 0, stream>>>(tokens, w1f, b1, W2, b2, probe); // FULL
    dtr_a1_probe<1><<<pg, 512, 0, stream>>>(tokens, w1f, b1, W2, b2, probe); // NOB
    dtr_a1_probe<2><<<pg, 512, 0, stream>>>(tokens, w1f, b1, W2, b2, probe); // NOSTAGE
    dtr_a1_probe<3><<<pg, 512, 0, stream>>>(tokens, w1f, b1, W2, b2, probe); // NOEPI
    dtr_a1_probe<4><<<pg, 512, 0, stream>>>(tokens, w1f, b1, W2, b2, probe); // MIN
    dtr_a1_probe<5><<<pg, 512, 0, stream>>>(tokens, w1f, b1, W2, b2, probe); // NOMFMA
}

// Round 16
// 199.028 us; speedup vs baseline: 4.9283x; 4.9283x over previous
//
#include <hip/hip_runtime.h>
#include <hip/hip_bf16.h>
#include <math.h>

#define NB    4
#define NTOK  8192
#define DIM   1024
#define HDIM  512
#define NKEEP 4096
#define MARG  0.06f     // PROVEN band (R6-R13): covers bf16-GEMM err (~1e-2
                        // max) + gelu_fast err (~1e-3); 2*eps ~ 0.025 < 0.06.
                        // 0.10 overflowed the 1024 candidate cap (R15 fail).
#define A2_MAXC 1024    // candidate capacity per batch (measured-safe at 0.06)

typedef __attribute__((ext_vector_type(8))) short bf16x8;
typedef __attribute__((ext_vector_type(4))) float f32x4;

__device__ __forceinline__ short f2bf(float x) {       // RNE f32->bf16
    unsigned u = __builtin_bit_cast(unsigned, x);
    unsigned r = (u + 0x7FFFu + ((u >> 16) & 1u)) >> 16;
    return (short)r;
}
__device__ __forceinline__ float gelu_exact(float h) {
    return 0.5f * h * (1.0f + erff(h * 0.70710678118654752f));
}
// tanh-form gelu (a1 only): g = h*sigmoid(2u), 2u = h*(c0 + c1*h^2).
// ~9 VALU ops vs erff's ~40+. |g - gelu_exact| <~ 1e-3; covered by MARG.
__device__ __forceinline__ float gelu_fast(float h) {
    const float t  = h * h;
    const float u2 = h * fmaf(0.07135481627f, t, 1.59576912161f);
    const float Z  = __expf(u2);
    return h - h / (Z + 1.0f);      // = h*Z/(Z+1), safe at Z=inf/0
}
__device__ __forceinline__ unsigned fkey(float x) {    // order-preserving flip
    const unsigned u = __builtin_bit_cast(unsigned, x);
    return u ^ ((u >> 31) ? 0xFFFFFFFFu : 0x80000000u);
}

// ---------------------------------------------------------------------------
// P0: repack W1 (fp32 [K=1024][N=512]) into bf16 MFMA-B fragment order.
// ---------------------------------------------------------------------------
__global__ __launch_bounds__(256)
void dtr_prep_w1(const float* __restrict__ W1, short* __restrict__ w1f)
{
    const int idx = blockIdx.x * 256 + threadIdx.x;    // 524288 total
    const int e = idx & 7, l = (idx >> 3) & 63, t = (idx >> 9) & 31, s = idx >> 14;
    const int k = s * 32 + (l >> 4) * 8 + e;
    const int n = t * 16 + (l & 15);
    w1f[idx] = f2bf(W1[(size_t)k * HDIM + n]);
}

// ---------------------------------------------------------------------------
// A1 v8 (geometry unchanged from R15; only MARG reverted): 512 blocks x 1024
// thr, 64 tokens/block -> B traffic 512 MB (v6 volume) at 16 waves/CU
// (v7 occupancy, 4/SIMD). Barrier-free K-loop; gelu_fast epilogue.
//  - A: 64 rows cvt'd once to LDS fragment order; ONE barrier. Conflict-free.
//  - B: w1f -> regs, 2-deep ping-pong, zero K-loop barriers.
//  - Wave w owns 2 ntiles (cols w*32..+31) x 64 tokens: acc[4][2] = 32 AGPR.
// ---------------------------------------------------------------------------
__global__ __launch_bounds__(1024, 4)
void dtr_a1_approx(const float* __restrict__ tokens,
                   const short* __restrict__ w1f,
                   const float* __restrict__ b1g,
                   const float* __restrict__ W2,
                   const float* __restrict__ b2g,
                   float* __restrict__ sapx)
{
    __shared__ __align__(16) short Af[65536];    // 128 KB: ((at*32+s)*64+l)*8
    __shared__ float part[16][64];               // 4 KB

    const int tid  = threadIdx.x;
    const int w    = tid >> 6;                   // 0..15
    const int lane = tid & 63;
    const int cl   = lane & 15;
    const int kg   = lane >> 4;
    const int tok0 = blockIdx.x * 64;

    // ---- stage A once: 8 bf16x8 pieces per thread (8192 total) ----
#pragma unroll
    for (int p = 0; p < 8; ++p) {
        const int idx = tid + p * 1024;          // 0..8191
        const int at  = idx >> 11;               // 0..3
        const int s   = (idx >> 6) & 31;         // 0..31
        const int l   = idx & 63;
        const int row = tok0 + at * 16 + (l & 15);
        const int kc  = s * 32 + (l >> 4) * 8;
        const float* g = tokens + (size_t)row * DIM + kc;
        const float4 f0 = *reinterpret_cast<const float4*>(g);
        const float4 f1 = *reinterpret_cast<const float4*>(g + 4);
        bf16x8 v;
        v[0] = f2bf(f0.x); v[1] = f2bf(f0.y); v[2] = f2bf(f0.z); v[3] = f2bf(f0.w);
        v[4] = f2bf(f1.x); v[5] = f2bf(f1.y); v[6] = f2bf(f1.z); v[7] = f2bf(f1.w);
        *reinterpret_cast<bf16x8*>(&Af[idx * 8]) = v;
    }
    __syncthreads();                             // the ONLY K-path barrier

    f32x4 acc[4][2];
#pragma unroll
    for (int at = 0; at < 4; ++at)
#pragma unroll
        for (int t = 0; t < 2; ++t) acc[at][t] = (f32x4){0.f, 0.f, 0.f, 0.f};

    // B fragment base: wave w owns ntiles w*2, w*2+1
    const short* bw = w1f + ((size_t)(w * 2) * 64 + lane) * 8;

    auto loadB = [&](int s, bf16x8* d) {
        const short* p = bw + (size_t)s * 16384;
#pragma unroll
        for (int t = 0; t < 2; ++t)
            d[t] = *reinterpret_cast<const bf16x8*>(p + t * 512);
    };
    auto compute = [&](int s, const bf16x8* bv) {
        bf16x8 af[4];
#pragma unroll
        for (int at = 0; at < 4; ++at)
            af[at] = *reinterpret_cast<const bf16x8*>(
                &Af[((at * 32 + s) * 64 + lane) * 8]);
#pragma unroll
        for (int t = 0; t < 2; ++t)
#pragma unroll
            for (int at = 0; at < 4; ++at)
                acc[at][t] = __builtin_amdgcn_mfma_f32_16x16x32_bf16(
                    af[at], bv[t], acc[at][t], 0, 0, 0);
    };

    bf16x8 bA[2], bB[2];
    loadB(0, bA);
#pragma unroll
    for (int s = 0; s < 32; s += 2) {
        if (s + 1 < 32) loadB(s + 1, bB);
        compute(s, bA);
        if (s + 2 < 32) loadB(s + 2, bA);
        compute(s + 1, bB);
    }

    // ---- epilogue: gelu_fast + W2 dot; D map col=lane&15, row=kg*4+r ----
    float pr[4][4];
#pragma unroll
    for (int at = 0; at < 4; ++at)
#pragma unroll
        for (int r = 0; r < 4; ++r) pr[at][r] = 0.f;
#pragma unroll
    for (int t = 0; t < 2; ++t) {
        const int n = (w * 2 + t) * 16 + cl;
        const float b1v = b1g[n], w2v = W2[n];
#pragma unroll
        for (int at = 0; at < 4; ++at)
#pragma unroll
            for (int r = 0; r < 4; ++r)
                pr[at][r] = fmaf(gelu_fast(acc[at][t][r] + b1v), w2v, pr[at][r]);
    }
#pragma unroll
    for (int at = 0; at < 4; ++at)
#pragma unroll
        for (int r = 0; r < 4; ++r) {
            float p = pr[at][r];
#pragma unroll
            for (int off = 1; off < 16; off <<= 1)
                p += __shfl_xor(p, off, 64);
            pr[at][r] = p;
        }
    if (cl == 0) {
#pragma unroll
        for (int at = 0; at < 4; ++at)
#pragma unroll
            for (int r = 0; r < 4; ++r)
                part[w][at * 16 + kg * 4 + r] = pr[at][r];
    }
    __syncthreads();
    if (tid < 64) {
        float s = b2g[0];
#pragma unroll
        for (int ww = 0; ww < 16; ++ww) s += part[ww][tid];
        sapx[tok0 + tid] = s;
    }
}

// ---------------------------------------------------------------------------
// Block-wide exclusive scan (1024 threads). lds >= 16 ints.
// ---------------------------------------------------------------------------
__device__ __forceinline__ int blk_excl_scan_1024(int v, int tid, int* lds, int* tot)
{
    const int lane = tid & 63;
    const int wid  = tid >> 6;
    int x = v;
#pragma unroll
    for (int d = 1; d < 64; d <<= 1) {
        const int y = __shfl_up(x, d, 64);
        if (lane >= d) x += y;
    }
    if (lane == 63) lds[wid] = x;
    __syncthreads();
    if (wid == 0) {
        int ww = (lane < 16) ? lds[lane] : 0;
#pragma unroll
        for (int d = 1; d < 16; d <<= 1) {
            const int y = __shfl_up(ww, d, 64);
            if (lane >= d) ww += y;
        }
        if (lane < 16) lds[lane] = ww;
    }
    __syncthreads();
    const int wave_off = (wid == 0) ? 0 : lds[wid - 1];
    const int total    = lds[15];
    __syncthreads();
    *tot = total;
    return wave_off + x - v;
}

// ---------------------------------------------------------------------------
// B1: radix-select exact 4096th-largest approx score; compact candidate band.
// ---------------------------------------------------------------------------
__global__ __launch_bounds__(1024)
void dtr_b1_cand(const float* __restrict__ sapx,
                 float* __restrict__ T_out, int* __restrict__ cnt_out,
                 int* __restrict__ cand)
{
    __shared__ int hist[256];
    __shared__ int scan_lds[16];
    __shared__ unsigned sh_pref;
    __shared__ int sh_rank;
    const int b = blockIdx.x, tid = threadIdx.x;
    const float* s = sapx + (size_t)b * NTOK;

    const int i0 = tid * 8;
    unsigned keys[8];
    float sc[8];
#pragma unroll
    for (int q = 0; q < 8; ++q) {
        sc[q] = s[i0 + q];
        keys[q] = fkey(sc[q]);
    }
    if (tid == 0) { sh_pref = 0u; sh_rank = NKEEP; }

    for (int level = 3; level >= 0; --level) {
        const int sh = level * 8;
        if (tid < 256) hist[tid] = 0;
        __syncthreads();
        const unsigned pref = sh_pref;
        const int rank = sh_rank;
#pragma unroll
        for (int q = 0; q < 8; ++q) {
            const unsigned u = keys[q];
            const bool match = (level == 3) || (((u ^ pref) >> (sh + 8)) == 0u);
            if (match) atomicAdd(&hist[(u >> sh) & 255], 1);
        }
        __syncthreads();
        const int v = (tid < 256) ? hist[255 - tid] : 0;
        int tot;
        const int pos = blk_excl_scan_1024(v, tid, scan_lds, &tot);
        if (tid < 256 && pos < rank && rank <= pos + v) {
            sh_pref = pref | ((unsigned)(255 - tid) << sh);
            sh_rank = rank - pos;
        }
        __syncthreads();
    }
    const unsigned ku = sh_pref;
    const unsigned tu = (ku & 0x80000000u) ? (ku ^ 0x80000000u) : ~ku;
    const float T = __builtin_bit_cast(float, tu);
    if (tid == 0) T_out[b] = T;

    int cf[8], cs = 0;
#pragma unroll
    for (int q = 0; q < 8; ++q) {
        cf[q] = (sc[q] >= T - MARG) && (sc[q] <= T + MARG);
        cs += cf[q];
    }
    int tot;
    int pos = blk_excl_scan_1024(cs, tid, scan_lds, &tot);
#pragma unroll
    for (int q = 0; q < 8; ++q)
        if (cf[q]) cand[(size_t)b * NTOK + pos++] = i0 + q;
    if (tid == 0) cnt_out[b] = (tot < A2_MAXC) ? tot : A2_MAXC;
}

// ---------------------------------------------------------------------------
// A2: exact fp32 rescore (exact erff -- authoritative for candidates).
// One block = 8 candidates, 256 threads; token rows staged in LDS once;
// K-loop barrier-free (W1 streamed from L2).
// ---------------------------------------------------------------------------
__global__ __launch_bounds__(256)
void dtr_a2_rescore(const float* __restrict__ tokens,
                    const float* __restrict__ W1,
                    const float* __restrict__ b1g,
                    const float* __restrict__ W2,
                    const float* __restrict__ b2g,
                    const int* __restrict__ cnt_in,
                    const int* __restrict__ cand,
                    float* __restrict__ sex)
{
    __shared__ __align__(16) float tk[8][DIM];   // 32 KB
    __shared__ float red[8][4];
    const int tid = threadIdx.x;
    const int b   = blockIdx.x >> 7;
    const int grp = blockIdx.x & 127;
    const int cnt = cnt_in[b];
    const int base = grp * 8;
    if (base >= cnt) return;

    int ctk[8];
#pragma unroll
    for (int c = 0; c < 8; ++c) {
        const int slot = base + c;
        ctk[c] = cand[(size_t)b * NTOK + (slot < cnt ? slot : base)];
    }
#pragma unroll
    for (int c = 0; c < 8; ++c) {
        const float4 v = *reinterpret_cast<const float4*>(
            tokens + ((size_t)b * NTOK + ctk[c]) * DIM + tid * 4);
        *reinterpret_cast<float4*>(&tk[c][tid * 4]) = v;
    }
    __syncthreads();

    const int j = tid * 2;
    float acc0[8], acc1[8];
#pragma unroll
    for (int c = 0; c < 8; ++c) { acc0[c] = 0.f; acc1[c] = 0.f; }

    for (int k0 = 0; k0 < DIM; k0 += 4) {
        float4 a[8];
#pragma unroll
        for (int c = 0; c < 8; ++c)
            a[c] = *reinterpret_cast<const float4*>(&tk[c][k0]);
#pragma unroll
        for (int kk = 0; kk < 4; ++kk) {
            const float2 wv = *reinterpret_cast<const float2*>(
                &W1[(size_t)(k0 + kk) * HDIM + j]);
#pragma unroll
            for (int c = 0; c < 8; ++c) {
                const float av = (kk == 0) ? a[c].x : (kk == 1) ? a[c].y
                               : (kk == 2) ? a[c].z : a[c].w;
                acc0[c] = fmaf(av, wv.x, acc0[c]);
                acc1[c] = fmaf(av, wv.y, acc1[c]);
            }
        }
    }

    const float b1v0 = b1g[j], b1v1 = b1g[j + 1];
    const float w20  = W2[j],  w21  = W2[j + 1];
    const int lane = tid & 63, w4 = tid >> 6;
#pragma unroll
    for (int c = 0; c < 8; ++c) {
        float p = fmaf(gelu_exact(acc0[c] + b1v0), w20,
                       gelu_exact(acc1[c] + b1v1) * w21);
#pragma unroll
        for (int off = 32; off > 0; off >>= 1)
            p += __shfl_xor(p, off, 64);
        if (lane == 0) red[c][w4] = p;
    }
    __syncthreads();
    if (tid < 8) {
        const int slot = base + tid;
        if (slot < cnt) {
            const float sv = red[tid][0] + red[tid][1] + red[tid][2]
                           + red[tid][3] + b2g[0];
            sex[(size_t)b * NTOK + cand[(size_t)b * NTOK + slot]] = sv;
        }
    }
}

// ---------------------------------------------------------------------------
// B2: final selection via radix-select on EXACT candidate scores.
// ---------------------------------------------------------------------------
__global__ __launch_bounds__(1024)
void dtr_b2_select(const float* __restrict__ sapx,
                   const float* __restrict__ sex,
                   const float* __restrict__ T_in,
                   const int* __restrict__ cnt_in,
                   const int* __restrict__ cand,
                   int* __restrict__ idx_out,
                   float* __restrict__ mask_out)
{
    __shared__ int hist[256];
    __shared__ int scan_lds[16];
    __shared__ unsigned sh_pref;
    __shared__ int sh_rank;
    __shared__ unsigned char kb[NTOK];
    const int b = blockIdx.x, tid = threadIdx.x;
    const float T  = T_in[b];
    const int  cnt = cnt_in[b];
    const float* s = sapx + (size_t)b * NTOK;

    const int i0 = tid * 8;
    int df[8], dsum = 0;
#pragma unroll
    for (int q = 0; q < 8; ++q) {
        df[q] = s[i0 + q] > T + MARG;
        dsum += df[q];
    }
    int n_in;
    (void)blk_excl_scan_1024(dsum, tid, scan_lds, &n_in);
    const int r = NKEEP - n_in;

    const bool valid = tid < cnt;
    const int  ctok  = valid ? cand[(size_t)b * NTOK + tid] : 0;
    const unsigned key = valid ? fkey(sex[(size_t)b * NTOK + ctok]) : 0u;
    for (int i = tid; i < NTOK; i += 1024) kb[i] = 0;
    if (tid == 0) { sh_pref = 0u; sh_rank = r; }

    for (int level = 3; level >= 0; --level) {
        const int sh = level * 8;
        if (tid < 256) hist[tid] = 0;
        __syncthreads();
        const unsigned pref = sh_pref;
        const int rank = sh_rank;
        const bool match = valid &&
            (level == 3 || (((key ^ pref) >> (sh + 8)) == 0u));
        if (match) atomicAdd(&hist[(key >> sh) & 255], 1);
        __syncthreads();
        const int v = (tid < 256) ? hist[255 - tid] : 0;
        int tot;
        const int pos = blk_excl_scan_1024(v, tid, scan_lds, &tot);
        if (tid < 256 && pos < rank && rank <= pos + v) {
            sh_pref = pref | ((unsigned)(255 - tid) << sh);
            sh_rank = rank - pos;
        }
        __syncthreads();
    }
    const unsigned Tkey = sh_pref;

    const int gt = valid && key > Tkey;
    const int eq = valid && key == Tkey;
    int tot_g, tot_e;
    (void)blk_excl_scan_1024(gt, tid, scan_lds, &tot_g);
    const int pos_e = blk_excl_scan_1024(eq, tid, scan_lds, &tot_e);
    const int need = r - tot_g;
    if ((gt || (eq && pos_e < need)) && valid) kb[ctok] = 1;
    __syncthreads();

    int kf[8], ks = 0;
#pragma unroll
    for (int q = 0; q < 8; ++q) {
        kf[q] = df[q] | (int)kb[i0 + q];
        ks += kf[q];
    }
    int tot;
    int pos = blk_excl_scan_1024(ks, tid, scan_lds, &tot);
#pragma unroll
    for (int q = 0; q < 8; ++q) {
        mask_out[(size_t)b * NTOK + i0 + q] = kf[q] ? 1.0f : 0.0f;
        if (kf[q]) idx_out[(size_t)b * NKEEP + pos++] = i0 + q;
    }
}

// ---------------------------------------------------------------------------
// Gather selected rows.
// ---------------------------------------------------------------------------
__global__ __launch_bounds__(256)
void dtr_gather_kernel(const float* __restrict__ tokens,
                       const int* __restrict__ idx,
                       float* __restrict__ selected)
{
    const int g   = blockIdx.x;
    const int b   = g >> 12;
    const int src = idx[g];
    const float4* sp = reinterpret_cast<const float4*>(
        tokens + ((size_t)b * NTOK + (size_t)src) * DIM);
    float4* dp = reinterpret_cast<float4*>(selected + (size_t)g * DIM);
    dp[threadIdx.x] = sp[threadIdx.x];
}

// ---------------------------------------------------------------------------
extern "C" void kernel_launch(void* const* d_in, const int* in_sizes, int n_in,
                              void* d_out, int out_size, void* d_ws, size_t ws_size,
                              hipStream_t stream)
{
    const float* tokens = (const float*)d_in[0];
    const float* W1     = (const float*)d_in[1];
    const float* b1     = (const float*)d_in[2];
    const float* W2     = (const float*)d_in[3];
    const float* b2     = (const float*)d_in[4];

    float* out      = (float*)d_out;
    float* selected = out;
    float* mask     = out + (size_t)NB * NKEEP * DIM;

    char* w = (char*)d_ws;
    float* sapx = (float*)(w);                 // 4*8192 f32
    float* sex  = (float*)(w + 131072);        // 4*8192 f32
    float* Tpx  = (float*)(w + 262144);        // 4 f32
    int*   ccnt = (int*)  (w + 262160);        // 4 i32
    int*   cand = (int*)  (w + 262400);        // 4*8192 i32
    short* w1f  = (short*)(w + 393472);        // 1 MB bf16
    int*   idx  = (int*)  (w + 1441792);       // 4*4096 i32

    dtr_prep_w1<<<2048, 256, 0, stream>>>(W1, w1f);
    dtr_a1_approx<<<(NB * NTOK) / 64, 1024, 0, stream>>>(tokens, w1f, b1, W2, b2, sapx);
    dtr_b1_cand<<<NB, 1024, 0, stream>>>(sapx, Tpx, ccnt, cand);
    dtr_a2_rescore<<<NB * 128, 256, 0, stream>>>(tokens, W1, b1, W2, b2, ccnt, cand, sex);
    dtr_b2_select<<<NB, 1024, 0, stream>>>(sapx, sex, Tpx, ccnt, cand, idx, mask);
    dtr_gather_kernel<<<NB * NKEEP, 256, 0, stream>>>(tokens, idx, selected);
}